// Round 1
// baseline (795.782 us; speedup 1.0000x reference)
//
#include <hip/hip_runtime.h>

typedef _Float16 f16;
typedef __bf16 bf16;
typedef f16 f16x4 __attribute__((ext_vector_type(4)));
typedef f16 f16x8 __attribute__((ext_vector_type(8)));
typedef bf16 bf16x4 __attribute__((ext_vector_type(4)));
typedef bf16 bf16x8 __attribute__((ext_vector_type(8)));
typedef float f32x4 __attribute__((ext_vector_type(4)));

#define SEQ 2048
#define HID 4096
#define NH 32
#define NKV 8
#define HD 128

__device__ __forceinline__ float fq_round(float x, float s){
  float r = rintf(x / s);
  r = fminf(fmaxf(r, -128.f), 127.f);
  return r * s;
}

// ---------------- fp32 -> bf16 convert (weights) ----------------
__global__ __launch_bounds__(256) void cvt_bf16_k(const float* __restrict__ x, bf16* __restrict__ y, int n4){
  int i = blockIdx.x * 256 + threadIdx.x;
  if (i < n4){
    float4 v = ((const float4*)x)[i];
    bf16x4 o = { (bf16)v.x, (bf16)v.y, (bf16)v.z, (bf16)v.w };
    ((bf16x4*)y)[i] = o;
  }
}

// ---------------- rope table: [SEQ][64] cos/sin ----------------
__global__ __launch_bounds__(256) void rope_table_k(const int* __restrict__ pos, float* __restrict__ cosT, float* __restrict__ sinT){
  int idx = blockIdx.x * 256 + threadIdx.x;  // SEQ*64
  int t = idx >> 6, j = idx & 63;
  float inv = powf(10000.f, -(float)j * (1.f/64.f));
  float f = (float)pos[t] * inv;
  cosT[idx] = cosf(f);
  sinT[idx] = sinf(f);
}

// ---------------- per-token fq of hidden_states ----------------
__global__ __launch_bounds__(256) void fq_hs_k(const float* __restrict__ h, const float* __restrict__ qb1, bf16* __restrict__ hs){
  int t = blockIdx.x, tid = threadIdx.x;
  const float* row = h + (size_t)t * HID;
  float x[16];
  float amax = 0.f;
  #pragma unroll
  for (int i = 0; i < 16; i++){
    int c = tid + i * 256;
    float v = row[c] - qb1[c];
    x[i] = v;
    amax = fmaxf(amax, fabsf(v));
  }
  #pragma unroll
  for (int d = 1; d < 64; d <<= 1) amax = fmaxf(amax, __shfl_xor(amax, d));
  __shared__ float red[4];
  if ((tid & 63) == 0) red[tid >> 6] = amax;
  __syncthreads();
  amax = fmaxf(fmaxf(red[0], red[1]), fmaxf(red[2], red[3]));
  float s = fmaxf(amax, 1e-8f) / 127.f;
  #pragma unroll
  for (int i = 0; i < 16; i++){
    int c = tid + i * 256;
    float q = fq_round(x[i], s) + qb1[c];
    hs[(size_t)t * HID + c] = (bf16)q;
  }
}

// ---------------- bf16 GEMM: A[2048,K] x B[N,K]^T -> C[2048,N] ----------------
__global__ __launch_bounds__(256) void gemm_bt(const bf16* __restrict__ A, const bf16* __restrict__ B,
                                               float* __restrict__ C, int N, int K){
  __shared__ bf16 As[128][40];
  __shared__ bf16 Bs[128][40];
  int bm = blockIdx.y * 128, bn = blockIdx.x * 128;
  int tid = threadIdx.x, wid = tid >> 6, lane = tid & 63;
  int wr = wid >> 1, wc = wid & 1;
  f32x4 acc[4][4] = {};
  for (int k0 = 0; k0 < K; k0 += 32){
    #pragma unroll
    for (int i = 0; i < 2; i++){
      int flat = i * 256 + tid;
      int r = flat >> 2, c = (flat & 3) * 8;
      *(bf16x8*)&As[r][c] = *(const bf16x8*)(A + (size_t)(bm + r) * K + k0 + c);
      *(bf16x8*)&Bs[r][c] = *(const bf16x8*)(B + (size_t)(bn + r) * K + k0 + c);
    }
    __syncthreads();
    bf16x8 af[4], bfr[4];
    #pragma unroll
    for (int mf = 0; mf < 4; mf++) af[mf] = *(bf16x8*)&As[wr*64 + mf*16 + (lane & 15)][(lane >> 4) * 8];
    #pragma unroll
    for (int nf = 0; nf < 4; nf++) bfr[nf] = *(bf16x8*)&Bs[wc*64 + nf*16 + (lane & 15)][(lane >> 4) * 8];
    #pragma unroll
    for (int mf = 0; mf < 4; mf++)
      #pragma unroll
      for (int nf = 0; nf < 4; nf++)
        acc[mf][nf] = __builtin_amdgcn_mfma_f32_16x16x32_bf16(af[mf], bfr[nf], acc[mf][nf], 0, 0, 0);
    __syncthreads();
  }
  int mrow = bm + wr * 64 + 4 * (lane >> 4);
  int ncol = bn + wc * 64 + (lane & 15);
  #pragma unroll
  for (int mf = 0; mf < 4; mf++)
    #pragma unroll
    for (int nf = 0; nf < 4; nf++)
      #pragma unroll
      for (int i = 0; i < 4; i++)
        C[(size_t)(mrow + mf * 16 + i) * N + ncol + nf * 16] = acc[mf][nf][i];
}

// ---------------- rope + per-token fq for Q -> f16 (scaled by 1/sqrt(128)) ----------------
__global__ __launch_bounds__(256) void rope_q_k(const float* __restrict__ qraw, const float* __restrict__ cosT,
                                                const float* __restrict__ sinT, f16* __restrict__ qf){
  int row = blockIdx.x * 4 + (threadIdx.x >> 6);  // [hh][t]
  int lane = threadIdx.x & 63;
  int hh = row >> 11, t = row & 2047;
  const float* qp = qraw + (size_t)t * HID + hh * HD;
  float q1 = qp[lane], q2 = qp[lane + 64];
  float c = cosT[t * 64 + lane], s = sinT[t * 64 + lane];
  float r1 = q1 * c - q2 * s;
  float r2 = q2 * c + q1 * s;
  float amax = fmaxf(fabsf(r1), fabsf(r2));
  #pragma unroll
  for (int d = 1; d < 64; d <<= 1) amax = fmaxf(amax, __shfl_xor(amax, d));
  float sc = fmaxf(amax, 1e-8f) / 127.f;
  const float kq = 0.08838834764831845f;  // 1/sqrt(128)
  f16* o = qf + ((size_t)hh * SEQ + t) * HD;
  o[lane]      = (f16)(fq_round(r1, sc) * kq);
  o[lane + 64] = (f16)(fq_round(r2, sc) * kq);
}

// ---------------- rope for K -> fp32 ----------------
__global__ __launch_bounds__(256) void rope_k_k(const float* __restrict__ kraw, const float* __restrict__ cosT,
                                                const float* __restrict__ sinT, float* __restrict__ krope){
  int row = blockIdx.x * 4 + (threadIdx.x >> 6);  // [kvh][t]
  int lane = threadIdx.x & 63;
  int kvh = row >> 11, t = row & 2047;
  const float* kp = kraw + (size_t)t * (NKV * HD) + kvh * HD;
  float k1 = kp[lane], k2 = kp[lane + 64];
  float c = cosT[t * 64 + lane], s = sinT[t * 64 + lane];
  float* o = krope + ((size_t)kvh * SEQ + t) * HD;
  o[lane]      = k1 * c - k2 * s;
  o[lane + 64] = k2 * c + k1 * s;
}

// ---------------- per-channel absmax for K (rope'd) and V ----------------
__global__ __launch_bounds__(256) void chmax_k(const float* __restrict__ krope, const float* __restrict__ vraw,
                                               float* __restrict__ kscale, float* __restrict__ vscale){
  int ch = blockIdx.x;  // 0..1023 K, 1024..2047 V
  int tid = threadIdx.x;
  float amax = 0.f;
  if (ch < 1024){
    int h = ch >> 7, d = ch & 127;
    const float* p = krope + (size_t)h * SEQ * HD + d;
    #pragma unroll
    for (int i = 0; i < 8; i++) amax = fmaxf(amax, fabsf(p[(size_t)(tid + i * 256) * HD]));
  } else {
    int c = ch - 1024;
    const float* p = vraw + c;
    #pragma unroll
    for (int i = 0; i < 8; i++) amax = fmaxf(amax, fabsf(p[(size_t)(tid + i * 256) * (NKV * HD)]));
  }
  #pragma unroll
  for (int d = 1; d < 64; d <<= 1) amax = fmaxf(amax, __shfl_xor(amax, d));
  __shared__ float red[4];
  if ((tid & 63) == 0) red[tid >> 6] = amax;
  __syncthreads();
  amax = fmaxf(fmaxf(red[0], red[1]), fmaxf(red[2], red[3]));
  if (tid == 0){
    float s = fmaxf(amax, 1e-8f) / 127.f;
    if (ch < 1024) kscale[ch] = s; else vscale[ch - 1024] = s;
  }
}

// ---------------- quantize K -> f16 [kvh][t][d] ----------------
__global__ __launch_bounds__(256) void quant_k_k(const float* __restrict__ krope, const float* __restrict__ kscale,
                                                 f16* __restrict__ kf){
  int idx = blockIdx.x * 256 + threadIdx.x;  // NKV*SEQ*HD
  int d = idx & 127;
  int h = idx >> 18;
  float s = kscale[(h << 7) + d];
  kf[idx] = (f16)fq_round(krope[idx], s);
}

// ---------------- quantize V -> f16 transposed [kvh][d][t] ----------------
__global__ __launch_bounds__(256) void quant_v_k(const float* __restrict__ vraw, const float* __restrict__ vscale,
                                                 f16* __restrict__ vt){
  int idx = blockIdx.x * 256 + threadIdx.x;  // [h][d][t]
  int h = idx >> 18, d = (idx >> 11) & 127, t = idx & 2047;
  float v = vraw[(size_t)t * (NKV * HD) + (h << 7) + d];
  float s = vscale[(h << 7) + d];
  vt[idx] = (f16)fq_round(v, s);
}

// ---------------- attention: 2-pass flash with quantized softmax ----------------
__global__ __launch_bounds__(256) void attn_k(const f16* __restrict__ qf, const f16* __restrict__ kf,
                                              const f16* __restrict__ vt, float* __restrict__ aout){
  int qt = blockIdx.x, hh = blockIdx.y;
  int kvh = hh >> 2;
  int tid = threadIdx.x, wid = tid >> 6, lane = tid & 63;
  __shared__ f16 qs[64][136];
  __shared__ f16 ks[64][136];
  __shared__ f16 vts[128][72];
  __shared__ f16 ps[4][16][72];

  {
    const f16* qbase = qf + ((size_t)hh * SEQ + qt * 64) * HD;
    #pragma unroll
    for (int i = 0; i < 8; i++){
      int flat = i * 256 + tid;
      int r = flat >> 5, c = (flat & 31) * 4;
      *(f16x4*)&qs[r][c] = *(const f16x4*)(qbase + r * HD + c);
    }
  }
  __syncthreads();
  f16x8 aq[4];
  #pragma unroll
  for (int kk = 0; kk < 4; kk++) aq[kk] = *(f16x8*)&qs[wid * 16 + (lane & 15)][kk * 32 + (lane >> 4) * 8];

  float m_i[4], l_i[4];
  #pragma unroll
  for (int i = 0; i < 4; i++){ m_i[i] = -1e30f; l_i[i] = 0.f; }
  int nkb = qt + 1;
  int qrow0 = qt * 64 + wid * 16 + 4 * (lane >> 4);
  int kcol0 = (lane & 15);

  // pass 1: online m, l
  for (int kb = 0; kb < nkb; kb++){
    __syncthreads();
    const f16* kbase = kf + ((size_t)kvh * SEQ + kb * 64) * HD;
    #pragma unroll
    for (int i = 0; i < 8; i++){
      int flat = i * 256 + tid;
      int r = flat >> 5, c = (flat & 31) * 4;
      *(f16x4*)&ks[r][c] = *(const f16x4*)(kbase + r * HD + c);
    }
    __syncthreads();
    f32x4 sacc[4];
    #pragma unroll
    for (int nf = 0; nf < 4; nf++){
      f32x4 a = {0.f, 0.f, 0.f, 0.f};
      #pragma unroll
      for (int kk = 0; kk < 4; kk++){
        f16x8 bk = *(f16x8*)&ks[nf * 16 + (lane & 15)][kk * 32 + (lane >> 4) * 8];
        a = __builtin_amdgcn_mfma_f32_16x16x32_f16(aq[kk], bk, a, 0, 0, 0);
      }
      sacc[nf] = a;
    }
    bool diag = (kb == qt);
    #pragma unroll
    for (int i = 0; i < 4; i++){
      float sv[4]; float bm = -1e30f;
      #pragma unroll
      for (int nf = 0; nf < 4; nf++){
        float sx = sacc[nf][i];
        if (diag && (kb * 64 + kcol0 + nf * 16 > qrow0 + i)) sx = -1e30f;
        sv[nf] = sx; bm = fmaxf(bm, sx);
      }
      #pragma unroll
      for (int d = 1; d < 16; d <<= 1) bm = fmaxf(bm, __shfl_xor(bm, d));
      float mn = fmaxf(m_i[i], bm);
      float psum = 0.f;
      #pragma unroll
      for (int nf = 0; nf < 4; nf++) psum += __expf(sv[nf] - mn);
      #pragma unroll
      for (int d = 1; d < 16; d <<= 1) psum += __shfl_xor(psum, d);
      l_i[i] = l_i[i] * __expf(m_i[i] - mn) + psum;
      m_i[i] = mn;
    }
  }

  float inv127l[4];
  #pragma unroll
  for (int i = 0; i < 4; i++) inv127l[i] = 1.f / (127.f * l_i[i]);
  f32x4 oacc[8] = {};

  // pass 2: recompute S, integer P, PV
  for (int kb = 0; kb < nkb; kb++){
    __syncthreads();
    const f16* kbase = kf + ((size_t)kvh * SEQ + kb * 64) * HD;
    #pragma unroll
    for (int i = 0; i < 8; i++){
      int flat = i * 256 + tid;
      int r = flat >> 5, c = (flat & 31) * 4;
      *(f16x4*)&ks[r][c] = *(const f16x4*)(kbase + r * HD + c);
    }
    const f16* vbase = vt + (size_t)kvh * HD * SEQ + kb * 64;
    #pragma unroll
    for (int i = 0; i < 8; i++){
      int flat = i * 256 + tid;
      int r = flat >> 4, c = (flat & 15) * 4;
      *(f16x4*)&vts[r][c] = *(const f16x4*)(vbase + (size_t)r * SEQ + c);
    }
    __syncthreads();
    f32x4 sacc[4];
    #pragma unroll
    for (int nf = 0; nf < 4; nf++){
      f32x4 a = {0.f, 0.f, 0.f, 0.f};
      #pragma unroll
      for (int kk = 0; kk < 4; kk++){
        f16x8 bk = *(f16x8*)&ks[nf * 16 + (lane & 15)][kk * 32 + (lane >> 4) * 8];
        a = __builtin_amdgcn_mfma_f32_16x16x32_f16(aq[kk], bk, a, 0, 0, 0);
      }
      sacc[nf] = a;
    }
    bool diag = (kb == qt);
    #pragma unroll
    for (int i = 0; i < 4; i++){
      #pragma unroll
      for (int nf = 0; nf < 4; nf++){
        float sx = sacc[nf][i];
        float p;
        if (diag && (kb * 64 + kcol0 + nf * 16 > qrow0 + i)) p = 0.f;
        else p = rintf(127.f * __expf(sx - m_i[i]));
        ps[wid][4 * (lane >> 4) + i][nf * 16 + (lane & 15)] = (f16)p;
      }
    }
    __syncthreads();
    f16x8 pa[2];
    #pragma unroll
    for (int kk = 0; kk < 2; kk++) pa[kk] = *(f16x8*)&ps[wid][lane & 15][kk * 32 + (lane >> 4) * 8];
    #pragma unroll
    for (int nf = 0; nf < 8; nf++){
      #pragma unroll
      for (int kk = 0; kk < 2; kk++){
        f16x8 vb = *(f16x8*)&vts[nf * 16 + (lane & 15)][kk * 32 + (lane >> 4) * 8];
        oacc[nf] = __builtin_amdgcn_mfma_f32_16x16x32_f16(pa[kk], vb, oacc[nf], 0, 0, 0);
      }
    }
  }

  // epilogue: per-row fq over HD
  float amax[4] = {0.f, 0.f, 0.f, 0.f};
  #pragma unroll
  for (int nf = 0; nf < 8; nf++)
    #pragma unroll
    for (int i = 0; i < 4; i++)
      amax[i] = fmaxf(amax[i], fabsf(oacc[nf][i] * inv127l[i]));
  #pragma unroll
  for (int i = 0; i < 4; i++){
    float a = amax[i];
    #pragma unroll
    for (int d = 1; d < 16; d <<= 1) a = fmaxf(a, __shfl_xor(a, d));
    amax[i] = a;
  }
  #pragma unroll
  for (int i = 0; i < 4; i++){
    float so = fmaxf(amax[i], 1e-8f) / 127.f;
    int row = qt * 64 + wid * 16 + 4 * (lane >> 4) + i;
    float* op = aout + ((size_t)hh * SEQ + row) * HD + (lane & 15);
    #pragma unroll
    for (int nf = 0; nf < 8; nf++){
      float v = oacc[nf][i] * inv127l[i];
      op[nf * 16] = fq_round(v, so);
    }
  }
}

// ---------------- epilogue: gather heads, *o_scale2, fq(out - qb2) + qb2 -> bf16 ----------------
__global__ __launch_bounds__(256) void epi_k(const float* __restrict__ aout, const float* __restrict__ osc,
                                             const float* __restrict__ qb2, bf16* __restrict__ act){
  int t = blockIdx.x, tid = threadIdx.x;
  float z[16]; float amax = 0.f;
  #pragma unroll
  for (int i = 0; i < 16; i++){
    int o = tid + i * 256;
    int h = o >> 7, d = o & 127;
    float y = aout[((size_t)h * SEQ + t) * HD + d] * osc[o];
    float zz = y - qb2[o];
    z[i] = zz;
    amax = fmaxf(amax, fabsf(zz));
  }
  #pragma unroll
  for (int d = 1; d < 64; d <<= 1) amax = fmaxf(amax, __shfl_xor(amax, d));
  __shared__ float red[4];
  if ((tid & 63) == 0) red[tid >> 6] = amax;
  __syncthreads();
  amax = fmaxf(fmaxf(red[0], red[1]), fmaxf(red[2], red[3]));
  float s = fmaxf(amax, 1e-8f) / 127.f;
  #pragma unroll
  for (int i = 0; i < 16; i++){
    int o = tid + i * 256;
    act[(size_t)t * HID + o] = (bf16)(fq_round(z[i], s) + qb2[o]);
  }
}

extern "C" void kernel_launch(void* const* d_in, const int* in_sizes, int n_in,
                              void* d_out, int out_size, void* d_ws, size_t ws_size,
                              hipStream_t stream) {
  const float* hidden = (const float*)d_in[0];
  const int*   pos    = (const int*)d_in[1];
  const float* Wq     = (const float*)d_in[2];
  const float* Wk     = (const float*)d_in[3];
  const float* Wv     = (const float*)d_in[4];
  const float* Wo     = (const float*)d_in[5];
  const float* qb1    = (const float*)d_in[6];
  const float* qb2    = (const float*)d_in[7];
  const float* osc    = (const float*)d_in[8];
  float* out = (float*)d_out;

  char* w = (char*)d_ws;
  size_t off = 0;
  auto take = [&](size_t b) -> char* {
    char* p = w + off;
    off += (b + 255) & ~(size_t)255;
    return p;
  };
  bf16* WqB   = (bf16*)take((size_t)HID * HID * 2);
  bf16* WkB   = (bf16*)take((size_t)NKV * HD * HID * 2);
  bf16* WvB   = (bf16*)take((size_t)NKV * HD * HID * 2);
  bf16* WoB   = (bf16*)take((size_t)HID * HID * 2);
  bf16* hsB   = (bf16*)take((size_t)SEQ * HID * 2);
  float* cosT = (float*)take((size_t)SEQ * 64 * 4);
  float* sinT = (float*)take((size_t)SEQ * 64 * 4);
  float* q_raw = (float*)take((size_t)SEQ * HID * 4);
  float* k_raw = (float*)take((size_t)SEQ * NKV * HD * 4);
  float* v_raw = (float*)take((size_t)SEQ * NKV * HD * 4);
  float* krope = (float*)take((size_t)NKV * SEQ * HD * 4);
  f16* qf  = (f16*)take((size_t)NH * SEQ * HD * 2);
  f16* kf  = (f16*)take((size_t)NKV * SEQ * HD * 2);
  f16* vtf = (f16*)take((size_t)NKV * HD * SEQ * 2);
  float* kscale = (float*)take(NKV * HD * 4);
  float* vscale = (float*)take(NKV * HD * 4);
  float* aout = q_raw;   // alias: q_raw dead after rope_q_k
  bf16*  act  = hsB;     // alias: hs dead after QKV GEMMs

  cvt_bf16_k<<<16384, 256, 0, stream>>>(Wq, WqB, 4194304);
  cvt_bf16_k<<<4096, 256, 0, stream>>>(Wk, WkB, 1048576);
  cvt_bf16_k<<<4096, 256, 0, stream>>>(Wv, WvB, 1048576);
  cvt_bf16_k<<<16384, 256, 0, stream>>>(Wo, WoB, 4194304);
  rope_table_k<<<512, 256, 0, stream>>>(pos, cosT, sinT);
  fq_hs_k<<<2048, 256, 0, stream>>>(hidden, qb1, hsB);
  gemm_bt<<<dim3(32, 16), 256, 0, stream>>>(hsB, WqB, q_raw, 4096, 4096);
  gemm_bt<<<dim3(8, 16), 256, 0, stream>>>(hsB, WkB, k_raw, 1024, 4096);
  gemm_bt<<<dim3(8, 16), 256, 0, stream>>>(hsB, WvB, v_raw, 1024, 4096);
  rope_q_k<<<16384, 256, 0, stream>>>(q_raw, cosT, sinT, qf);
  rope_k_k<<<4096, 256, 0, stream>>>(k_raw, cosT, sinT, krope);
  chmax_k<<<2048, 256, 0, stream>>>(krope, v_raw, kscale, vscale);
  quant_k_k<<<8192, 256, 0, stream>>>(krope, kscale, kf);
  quant_v_k<<<8192, 256, 0, stream>>>(v_raw, vscale, vtf);
  attn_k<<<dim3(32, 32), 256, 0, stream>>>(qf, kf, vtf, aout);
  epi_k<<<2048, 256, 0, stream>>>(aout, osc, qb2, act);
  gemm_bt<<<dim3(32, 16), 256, 0, stream>>>(act, WoB, out, 4096, 4096);
}

// Round 2
// 690.154 us; speedup vs baseline: 1.1530x; 1.1530x over previous
//
#include <hip/hip_runtime.h>
#include <stdint.h>

typedef _Float16 f16;
typedef __bf16 bf16;
typedef f16 f16x4 __attribute__((ext_vector_type(4)));
typedef f16 f16x8 __attribute__((ext_vector_type(8)));
typedef bf16 bf16x4 __attribute__((ext_vector_type(4)));
typedef bf16 bf16x8 __attribute__((ext_vector_type(8)));
typedef float f32x4 __attribute__((ext_vector_type(4)));

#define SEQ 2048
#define HID 4096
#define NH 32
#define NKV 8
#define HD 128

__device__ __forceinline__ float fq_round(float x, float s){
  float r = rintf(x / s);
  r = fminf(fmaxf(r, -128.f), 127.f);
  return r * s;
}

__device__ __forceinline__ void gload_lds16(const void* g, void* l){
  __builtin_amdgcn_global_load_lds(
      (const __attribute__((address_space(1))) uint32_t*)g,
      (__attribute__((address_space(3))) uint32_t*)l, 16, 0, 0);
}

// stage a [128 rows][8 granules-of-16B] tile (row = 64 f16/bf16), XOR-swizzled
__device__ __forceinline__ void stage_g8(const void* gbase, size_t row_bytes, void* lds, int tid){
  int w = tid >> 6, l = tid & 63;
  #pragma unroll
  for (int i = 0; i < 4; i++){
    int flat = i * 256 + w * 64 + l;
    int r = flat >> 3, g = flat & 7;
    const char* src = (const char*)gbase + (size_t)r * row_bytes + (size_t)((g ^ (r & 7)) << 4);
    char* dst = (char*)lds + (size_t)(i * 256 + w * 64) * 16;
    gload_lds16(src, dst);
  }
}
// stage a [64 rows][16 granules-of-16B] tile (row = 128 f16), XOR-swizzled
__device__ __forceinline__ void stage_g16(const void* gbase, size_t row_bytes, void* lds, int tid){
  int w = tid >> 6, l = tid & 63;
  #pragma unroll
  for (int i = 0; i < 4; i++){
    int flat = i * 256 + w * 64 + l;
    int r = flat >> 4, g = flat & 15;
    const char* src = (const char*)gbase + (size_t)r * row_bytes + (size_t)((g ^ (r & 15)) << 4);
    char* dst = (char*)lds + (size_t)(i * 256 + w * 64) * 16;
    gload_lds16(src, dst);
  }
}

// ---------------- fp32 -> bf16 convert (weights) ----------------
__global__ __launch_bounds__(256) void cvt_bf16_k(const float* __restrict__ x, bf16* __restrict__ y, int n4){
  int i = blockIdx.x * 256 + threadIdx.x;
  if (i < n4){
    float4 v = ((const float4*)x)[i];
    bf16x4 o = { (bf16)v.x, (bf16)v.y, (bf16)v.z, (bf16)v.w };
    ((bf16x4*)y)[i] = o;
  }
}

// ---------------- rope table: [SEQ][64] cos/sin ----------------
__global__ __launch_bounds__(256) void rope_table_k(const int* __restrict__ pos, float* __restrict__ cosT, float* __restrict__ sinT){
  int idx = blockIdx.x * 256 + threadIdx.x;
  int t = idx >> 6, j = idx & 63;
  float inv = powf(10000.f, -(float)j * (1.f/64.f));
  float f = (float)pos[t] * inv;
  cosT[idx] = cosf(f);
  sinT[idx] = sinf(f);
}

// ---------------- per-token fq of hidden_states ----------------
__global__ __launch_bounds__(256) void fq_hs_k(const float* __restrict__ h, const float* __restrict__ qb1, bf16* __restrict__ hs){
  int t = blockIdx.x, tid = threadIdx.x;
  const float* row = h + (size_t)t * HID;
  float x[16];
  float amax = 0.f;
  #pragma unroll
  for (int i = 0; i < 16; i++){
    int c = tid + i * 256;
    float v = row[c] - qb1[c];
    x[i] = v;
    amax = fmaxf(amax, fabsf(v));
  }
  #pragma unroll
  for (int d = 1; d < 64; d <<= 1) amax = fmaxf(amax, __shfl_xor(amax, d));
  __shared__ float red[4];
  if ((tid & 63) == 0) red[tid >> 6] = amax;
  __syncthreads();
  amax = fmaxf(fmaxf(red[0], red[1]), fmaxf(red[2], red[3]));
  float s = fmaxf(amax, 1e-8f) / 127.f;
  #pragma unroll
  for (int i = 0; i < 16; i++){
    int c = tid + i * 256;
    float q = fq_round(x[i], s) + qb1[c];
    hs[(size_t)t * HID + c] = (bf16)q;
  }
}

// ---------------- bf16 GEMM: A[2048,K] x B[N,K]^T -> C[2048,N], BK=64 + gload_lds ----------------
__global__ __launch_bounds__(256) void gemm_bt(const bf16* __restrict__ A, const bf16* __restrict__ B,
                                               float* __restrict__ C, int N, int K){
  __shared__ bf16 As[128 * 64];
  __shared__ bf16 Bs[128 * 64];
  int bm = blockIdx.y * 128, bn = blockIdx.x * 128;
  int tid = threadIdx.x, wid = tid >> 6, lane = tid & 63;
  int wr = wid >> 1, wc = wid & 1;
  f32x4 acc[4][4] = {};
  for (int k0 = 0; k0 < K; k0 += 64){
    __syncthreads();
    stage_g8(A + (size_t)bm * K + k0, (size_t)K * 2, As, tid);
    stage_g8(B + (size_t)bn * K + k0, (size_t)K * 2, Bs, tid);
    asm volatile("s_waitcnt vmcnt(0)" ::: "memory");
    __syncthreads();
    #pragma unroll
    for (int ks2 = 0; ks2 < 2; ks2++){
      bf16x8 af[4], bfr[4];
      int g = ks2 * 4 + (lane >> 4);
      #pragma unroll
      for (int mf = 0; mf < 4; mf++){
        int rr = wr * 64 + mf * 16 + (lane & 15);
        af[mf] = *(const bf16x8*)(As + rr * 64 + ((g ^ (rr & 7)) << 3));
      }
      #pragma unroll
      for (int nf = 0; nf < 4; nf++){
        int rr = wc * 64 + nf * 16 + (lane & 15);
        bfr[nf] = *(const bf16x8*)(Bs + rr * 64 + ((g ^ (rr & 7)) << 3));
      }
      #pragma unroll
      for (int mf = 0; mf < 4; mf++)
        #pragma unroll
        for (int nf = 0; nf < 4; nf++)
          acc[mf][nf] = __builtin_amdgcn_mfma_f32_16x16x32_bf16(af[mf], bfr[nf], acc[mf][nf], 0, 0, 0);
    }
  }
  int mrow = bm + wr * 64 + 4 * (lane >> 4);
  int ncol = bn + wc * 64 + (lane & 15);
  #pragma unroll
  for (int mf = 0; mf < 4; mf++)
    #pragma unroll
    for (int nf = 0; nf < 4; nf++)
      #pragma unroll
      for (int i = 0; i < 4; i++)
        C[(size_t)(mrow + mf * 16 + i) * N + ncol + nf * 16] = acc[mf][nf][i];
}

// ---------------- rope + per-token fq for Q -> f16 (scaled by 1/sqrt(128)) ----------------
__global__ __launch_bounds__(256) void rope_q_k(const float* __restrict__ qraw, const float* __restrict__ cosT,
                                                const float* __restrict__ sinT, f16* __restrict__ qf){
  int row = blockIdx.x * 4 + (threadIdx.x >> 6);
  int lane = threadIdx.x & 63;
  int hh = row >> 11, t = row & 2047;
  const float* qp = qraw + (size_t)t * HID + hh * HD;
  float q1 = qp[lane], q2 = qp[lane + 64];
  float c = cosT[t * 64 + lane], s = sinT[t * 64 + lane];
  float r1 = q1 * c - q2 * s;
  float r2 = q2 * c + q1 * s;
  float amax = fmaxf(fabsf(r1), fabsf(r2));
  #pragma unroll
  for (int d = 1; d < 64; d <<= 1) amax = fmaxf(amax, __shfl_xor(amax, d));
  float sc = fmaxf(amax, 1e-8f) / 127.f;
  const float kq = 0.08838834764831845f;
  f16* o = qf + ((size_t)hh * SEQ + t) * HD;
  o[lane]      = (f16)(fq_round(r1, sc) * kq);
  o[lane + 64] = (f16)(fq_round(r2, sc) * kq);
}

// ---------------- rope for K -> fp32 ----------------
__global__ __launch_bounds__(256) void rope_k_k(const float* __restrict__ kraw, const float* __restrict__ cosT,
                                                const float* __restrict__ sinT, float* __restrict__ krope){
  int row = blockIdx.x * 4 + (threadIdx.x >> 6);
  int lane = threadIdx.x & 63;
  int kvh = row >> 11, t = row & 2047;
  const float* kp = kraw + (size_t)t * (NKV * HD) + kvh * HD;
  float k1 = kp[lane], k2 = kp[lane + 64];
  float c = cosT[t * 64 + lane], s = sinT[t * 64 + lane];
  float* o = krope + ((size_t)kvh * SEQ + t) * HD;
  o[lane]      = k1 * c - k2 * s;
  o[lane + 64] = k2 * c + k1 * s;
}

// ---------------- per-channel absmax (coalesced partials + atomicMax) ----------------
__global__ __launch_bounds__(256) void kmax_part(const float* __restrict__ krope, float* __restrict__ kamax){
  int kvh = blockIdx.x >> 3, slice = blockIdx.x & 7;
  int c = threadIdx.x & 127, rh = threadIdx.x >> 7;
  const float* p = krope + ((size_t)kvh * SEQ + slice * 256 + rh) * HD + c;
  float a = 0.f;
  #pragma unroll 8
  for (int r = 0; r < 128; r++) a = fmaxf(a, fabsf(p[(size_t)r * 2 * HD]));
  atomicMax((int*)&kamax[kvh * 128 + c], __float_as_int(a));
}

__global__ __launch_bounds__(256) void vmax_part(const float* __restrict__ vraw, float* __restrict__ vamax){
  int slice = blockIdx.x;
  int tid = threadIdx.x;
  const float4* p = (const float4*)vraw;
  float a0 = 0.f, a1 = 0.f, a2 = 0.f, a3 = 0.f;
  for (int r = 0; r < 256; r++){
    float4 v = p[(size_t)(slice * 256 + r) * 256 + tid];
    a0 = fmaxf(a0, fabsf(v.x)); a1 = fmaxf(a1, fabsf(v.y));
    a2 = fmaxf(a2, fabsf(v.z)); a3 = fmaxf(a3, fabsf(v.w));
  }
  atomicMax((int*)&vamax[tid * 4 + 0], __float_as_int(a0));
  atomicMax((int*)&vamax[tid * 4 + 1], __float_as_int(a1));
  atomicMax((int*)&vamax[tid * 4 + 2], __float_as_int(a2));
  atomicMax((int*)&vamax[tid * 4 + 3], __float_as_int(a3));
}

// ---------------- quantize K -> f16 [kvh][t][d] ----------------
__global__ __launch_bounds__(256) void quant_k_k(const float* __restrict__ krope, const float* __restrict__ kamax,
                                                 f16* __restrict__ kf){
  int idx = blockIdx.x * 256 + threadIdx.x;
  int d = idx & 127;
  int h = idx >> 18;
  float s = fmaxf(kamax[(h << 7) + d], 1e-8f) / 127.f;
  kf[idx] = (f16)fq_round(krope[idx], s);
}

// ---------------- quantize V -> f16 transposed [kvh][d][t], LDS-tiled transpose ----------------
__global__ __launch_bounds__(256) void quant_v_k(const float* __restrict__ vraw, const float* __restrict__ vamax,
                                                 f16* __restrict__ vt){
  __shared__ float tile[64][65];
  int t0 = blockIdx.x * 64;
  int c0 = blockIdx.y * 64;
  int tx = threadIdx.x & 63, ty = threadIdx.x >> 6;
  #pragma unroll
  for (int i = 0; i < 16; i++){
    int r = i * 4 + ty;
    tile[r][tx] = vraw[(size_t)(t0 + r) * 1024 + c0 + tx];
  }
  __syncthreads();
  #pragma unroll
  for (int i = 0; i < 16; i++){
    int dch = i * 4 + ty;
    int ch = c0 + dch;
    float s = fmaxf(vamax[ch], 1e-8f) / 127.f;
    vt[(size_t)ch * SEQ + t0 + tx] = (f16)fq_round(tile[tx][dch], s);
  }
}

// ---------------- attention: paired causal q-tiles, shared K/V staging ----------------
__global__ __launch_bounds__(256) void attn_k(const f16* __restrict__ qf, const f16* __restrict__ kf,
                                              const f16* __restrict__ vt, float* __restrict__ aout){
  int pr = blockIdx.x;            // 0..15
  int hh = blockIdx.y;            // 0..31
  int qtA = pr, qtB = 31 - pr;    // paired tiles: work = 33 iters for every block
  int kvh = hh >> 2;
  int tid = threadIdx.x, wid = tid >> 6, lane = tid & 63;

  __shared__ f16 ks[64 * 128];
  __shared__ f16 vs[128 * 64];
  __shared__ f16 ps[2][4][16][72];

  int kcol0 = lane & 15;
  int qrow0A = qtA * 64 + wid * 16 + 4 * (lane >> 4);
  int qrow0B = qtB * 64 + wid * 16 + 4 * (lane >> 4);

  // Q fragments direct from global
  f16x8 aqA[4], aqB[4];
  {
    int qrA = qtA * 64 + wid * 16 + (lane & 15);
    int qrB = qtB * 64 + wid * 16 + (lane & 15);
    #pragma unroll
    for (int kk = 0; kk < 4; kk++){
      int c = kk * 32 + (lane >> 4) * 8;
      aqA[kk] = *(const f16x8*)(qf + ((size_t)hh * SEQ + qrA) * HD + c);
      aqB[kk] = *(const f16x8*)(qf + ((size_t)hh * SEQ + qrB) * HD + c);
    }
  }

  auto qk_tile = [&](f16x8* aq, f32x4* sacc){
    #pragma unroll
    for (int nf = 0; nf < 4; nf++){
      f32x4 a = {0.f, 0.f, 0.f, 0.f};
      int rr = nf * 16 + (lane & 15);
      #pragma unroll
      for (int kk = 0; kk < 4; kk++){
        int c = kk * 32 + (lane >> 4) * 8;
        f16x8 bk = *(const f16x8*)(ks + rr * 128 + (((c >> 3) ^ (rr & 15)) << 3));
        a = __builtin_amdgcn_mfma_f32_16x16x32_f16(aq[kk], bk, a, 0, 0, 0);
      }
      sacc[nf] = a;
    }
  };

  auto online = [&](f32x4* sacc, int kb, int qt, int qrow0, float* m_i, float* l_i){
    bool diag = (kb == qt);
    #pragma unroll
    for (int i = 0; i < 4; i++){
      float sv[4]; float bm2 = -1e30f;
      #pragma unroll
      for (int nf = 0; nf < 4; nf++){
        float sx = sacc[nf][i];
        if (diag && (kb * 64 + kcol0 + nf * 16 > qrow0 + i)) sx = -1e30f;
        sv[nf] = sx; bm2 = fmaxf(bm2, sx);
      }
      #pragma unroll
      for (int d = 1; d < 16; d <<= 1) bm2 = fmaxf(bm2, __shfl_xor(bm2, d));
      float mn = fmaxf(m_i[i], bm2);
      float psum = 0.f;
      #pragma unroll
      for (int nf = 0; nf < 4; nf++) psum += __expf(sv[nf] - mn);
      #pragma unroll
      for (int d = 1; d < 16; d <<= 1) psum += __shfl_xor(psum, d);
      l_i[i] = l_i[i] * __expf(m_i[i] - mn) + psum;
      m_i[i] = mn;
    }
  };

  float mA[4], lA[4], mB[4], lB[4];
  #pragma unroll
  for (int i = 0; i < 4; i++){ mA[i] = -1e30f; lA[i] = 0.f; mB[i] = -1e30f; lB[i] = 0.f; }

  // pass 1: online m, l (staged K shared by both halves)
  for (int kb = 0; kb <= qtB; kb++){
    __syncthreads();
    stage_g16(kf + ((size_t)kvh * SEQ + kb * 64) * HD, (size_t)HD * 2, ks, tid);
    asm volatile("s_waitcnt vmcnt(0)" ::: "memory");
    __syncthreads();
    {
      f32x4 sacc[4];
      qk_tile(aqB, sacc);
      online(sacc, kb, qtB, qrow0B, mB, lB);
    }
    if (kb <= qtA){
      f32x4 sacc[4];
      qk_tile(aqA, sacc);
      online(sacc, kb, qtA, qrow0A, mA, lA);
    }
  }

  float i127A[4], i127B[4];
  #pragma unroll
  for (int i = 0; i < 4; i++){ i127A[i] = 1.f / (127.f * lA[i]); i127B[i] = 1.f / (127.f * lB[i]); }
  f32x4 oaccA[8] = {}, oaccB[8] = {};

  auto p_write = [&](f32x4* sacc, int kb, int qt, int qrow0, float* m_i, int half){
    bool diag = (kb == qt);
    #pragma unroll
    for (int i = 0; i < 4; i++){
      #pragma unroll
      for (int nf = 0; nf < 4; nf++){
        float sx = sacc[nf][i];
        float p;
        if (diag && (kb * 64 + kcol0 + nf * 16 > qrow0 + i)) p = 0.f;
        else p = rintf(127.f * __expf(sx - m_i[i]));
        ps[half][wid][4 * (lane >> 4) + i][nf * 16 + (lane & 15)] = (f16)p;
      }
    }
  };

  auto pv_acc = [&](int half, f32x4* oacc){
    f16x8 pa[2];
    #pragma unroll
    for (int kk = 0; kk < 2; kk++) pa[kk] = *(const f16x8*)&ps[half][wid][lane & 15][kk * 32 + (lane >> 4) * 8];
    #pragma unroll
    for (int nf = 0; nf < 8; nf++){
      int rr = nf * 16 + (lane & 15);
      #pragma unroll
      for (int kk = 0; kk < 2; kk++){
        int c = kk * 32 + (lane >> 4) * 8;
        f16x8 vb = *(const f16x8*)(vs + rr * 64 + (((c >> 3) ^ (rr & 7)) << 3));
        oacc[nf] = __builtin_amdgcn_mfma_f32_16x16x32_f16(pa[kk], vb, oacc[nf], 0, 0, 0);
      }
    }
  };

  // pass 2: exact integer P + PV
  for (int kb = 0; kb <= qtB; kb++){
    __syncthreads();
    stage_g16(kf + ((size_t)kvh * SEQ + kb * 64) * HD, (size_t)HD * 2, ks, tid);
    stage_g8(vt + (size_t)kvh * HD * SEQ + kb * 64, (size_t)SEQ * 2, vs, tid);
    asm volatile("s_waitcnt vmcnt(0)" ::: "memory");
    __syncthreads();
    bool doA = (kb <= qtA);
    {
      f32x4 sacc[4];
      qk_tile(aqB, sacc);
      p_write(sacc, kb, qtB, qrow0B, mB, 1);
    }
    if (doA){
      f32x4 sacc[4];
      qk_tile(aqA, sacc);
      p_write(sacc, kb, qtA, qrow0A, mA, 0);
    }
    __syncthreads();
    pv_acc(1, oaccB);
    if (doA) pv_acc(0, oaccA);
  }

  // epilogue: per-row fq over HD, per half
  auto epilogue = [&](f32x4* oacc, float* i127, int qt){
    float am[4] = {0.f, 0.f, 0.f, 0.f};
    #pragma unroll
    for (int nf = 0; nf < 8; nf++)
      #pragma unroll
      for (int i = 0; i < 4; i++)
        am[i] = fmaxf(am[i], fabsf(oacc[nf][i] * i127[i]));
    #pragma unroll
    for (int i = 0; i < 4; i++){
      float a = am[i];
      #pragma unroll
      for (int d = 1; d < 16; d <<= 1) a = fmaxf(a, __shfl_xor(a, d));
      am[i] = a;
    }
    #pragma unroll
    for (int i = 0; i < 4; i++){
      float so = fmaxf(am[i], 1e-8f) / 127.f;
      int row = qt * 64 + wid * 16 + 4 * (lane >> 4) + i;
      float* op = aout + ((size_t)hh * SEQ + row) * HD + (lane & 15);
      #pragma unroll
      for (int nf = 0; nf < 8; nf++){
        float v = oacc[nf][i] * i127[i];
        op[nf * 16] = fq_round(v, so);
      }
    }
  };
  epilogue(oaccB, i127B, qtB);
  epilogue(oaccA, i127A, qtA);
}

// ---------------- epilogue: gather heads, *o_scale2, fq(out - qb2) + qb2 -> bf16 ----------------
__global__ __launch_bounds__(256) void epi_k(const float* __restrict__ aout, const float* __restrict__ osc,
                                             const float* __restrict__ qb2, bf16* __restrict__ act){
  int t = blockIdx.x, tid = threadIdx.x;
  float z[16]; float amax = 0.f;
  #pragma unroll
  for (int i = 0; i < 16; i++){
    int o = tid + i * 256;
    int h = o >> 7, d = o & 127;
    float y = aout[((size_t)h * SEQ + t) * HD + d] * osc[o];
    float zz = y - qb2[o];
    z[i] = zz;
    amax = fmaxf(amax, fabsf(zz));
  }
  #pragma unroll
  for (int d = 1; d < 64; d <<= 1) amax = fmaxf(amax, __shfl_xor(amax, d));
  __shared__ float red[4];
  if ((tid & 63) == 0) red[tid >> 6] = amax;
  __syncthreads();
  amax = fmaxf(fmaxf(red[0], red[1]), fmaxf(red[2], red[3]));
  float s = fmaxf(amax, 1e-8f) / 127.f;
  #pragma unroll
  for (int i = 0; i < 16; i++){
    int o = tid + i * 256;
    act[(size_t)t * HID + o] = (bf16)(fq_round(z[i], s) + qb2[o]);
  }
}

extern "C" void kernel_launch(void* const* d_in, const int* in_sizes, int n_in,
                              void* d_out, int out_size, void* d_ws, size_t ws_size,
                              hipStream_t stream) {
  const float* hidden = (const float*)d_in[0];
  const int*   pos    = (const int*)d_in[1];
  const float* Wq     = (const float*)d_in[2];
  const float* Wk     = (const float*)d_in[3];
  const float* Wv     = (const float*)d_in[4];
  const float* Wo     = (const float*)d_in[5];
  const float* qb1    = (const float*)d_in[6];
  const float* qb2    = (const float*)d_in[7];
  const float* osc    = (const float*)d_in[8];
  float* out = (float*)d_out;

  char* w = (char*)d_ws;
  size_t off = 0;
  auto take = [&](size_t b) -> char* {
    char* p = w + off;
    off += (b + 255) & ~(size_t)255;
    return p;
  };
  bf16* WqB   = (bf16*)take((size_t)HID * HID * 2);
  bf16* WkB   = (bf16*)take((size_t)NKV * HD * HID * 2);
  bf16* WvB   = (bf16*)take((size_t)NKV * HD * HID * 2);
  bf16* WoB   = (bf16*)take((size_t)HID * HID * 2);
  bf16* hsB   = (bf16*)take((size_t)SEQ * HID * 2);
  float* cosT = (float*)take((size_t)SEQ * 64 * 4);
  float* sinT = (float*)take((size_t)SEQ * 64 * 4);
  float* q_raw = (float*)take((size_t)SEQ * HID * 4);
  float* k_raw = (float*)take((size_t)SEQ * NKV * HD * 4);
  float* v_raw = (float*)take((size_t)SEQ * NKV * HD * 4);
  float* krope = (float*)take((size_t)NKV * SEQ * HD * 4);
  f16* qf  = (f16*)take((size_t)NH * SEQ * HD * 2);
  f16* kf  = (f16*)take((size_t)NKV * SEQ * HD * 2);
  f16* vtf = (f16*)take((size_t)NKV * HD * SEQ * 2);
  float* kvamax = (float*)take(2048 * 4);
  float* kamax = kvamax, *vamax = kvamax + 1024;
  float* aout = q_raw;   // alias: q_raw dead after rope_q_k
  bf16*  act  = hsB;     // alias: hs dead after QKV GEMMs

  hipMemsetAsync(kvamax, 0, 2048 * sizeof(float), stream);
  cvt_bf16_k<<<16384, 256, 0, stream>>>(Wq, WqB, 4194304);
  cvt_bf16_k<<<4096, 256, 0, stream>>>(Wk, WkB, 1048576);
  cvt_bf16_k<<<4096, 256, 0, stream>>>(Wv, WvB, 1048576);
  cvt_bf16_k<<<16384, 256, 0, stream>>>(Wo, WoB, 4194304);
  rope_table_k<<<512, 256, 0, stream>>>(pos, cosT, sinT);
  fq_hs_k<<<2048, 256, 0, stream>>>(hidden, qb1, hsB);
  gemm_bt<<<dim3(32, 16), 256, 0, stream>>>(hsB, WqB, q_raw, 4096, 4096);
  gemm_bt<<<dim3(8, 16), 256, 0, stream>>>(hsB, WkB, k_raw, 1024, 4096);
  gemm_bt<<<dim3(8, 16), 256, 0, stream>>>(hsB, WvB, v_raw, 1024, 4096);
  rope_q_k<<<16384, 256, 0, stream>>>(q_raw, cosT, sinT, qf);
  rope_k_k<<<4096, 256, 0, stream>>>(k_raw, cosT, sinT, krope);
  kmax_part<<<64, 256, 0, stream>>>(krope, kamax);
  vmax_part<<<8, 256, 0, stream>>>(v_raw, vamax);
  quant_k_k<<<8192, 256, 0, stream>>>(krope, kamax, kf);
  quant_v_k<<<dim3(32, 16), 256, 0, stream>>>(v_raw, vamax, vtf);
  attn_k<<<dim3(16, 32), 256, 0, stream>>>(qf, kf, vtf, aout);
  epi_k<<<2048, 256, 0, stream>>>(aout, osc, qb2, act);
  gemm_bt<<<dim3(32, 16), 256, 0, stream>>>(act, WoB, out, 4096, 4096);
}